// Round 4
// baseline (1509.655 us; speedup 1.0000x reference)
//
#include <hip/hip_runtime.h>
#include <hip/hip_bf16.h>

namespace {

constexpr int Sn = 2048;
constexpr int Dn = 128;
constexpr int BM = 64;           // q rows per workgroup
constexpr int BN = 32;           // k cols per tile
constexpr int THREADS = 256;     // 4 waves
constexpr int NT = Sn / BN;      // 64 k-tiles
constexpr long long OUT0 = 4LL * 16 * Sn * Dn;   // attn_output elems before weights

constexpr int KSTR = 136;        // ushorts per K-layout row (128 + 8 pad)
constexpr int VSTR = 34;         // ushorts per vt/w row (32 + 2 pad)
constexpr int KT = BN * KSTR;    // 4352 ushorts per K tile
constexpr int VT = Dn * VSTR;    // 4352 ushorts per V^T tile
constexpr int WT = BM * VSTR;    // 2176 ushorts for w tile

typedef short s16x4 __attribute__((ext_vector_type(4)));
typedef float f32x4 __attribute__((ext_vector_type(4)));

__device__ __forceinline__ unsigned short f2bu(float x) {
    return __bfloat16_as_ushort(__float2bfloat16(x));   // RNE
}
__device__ __forceinline__ unsigned pk2(float lo, float hi) {
    return (unsigned)f2bu(lo) | ((unsigned)f2bu(hi) << 16);
}
__device__ __forceinline__ float b2f(unsigned short u) {
    union { unsigned u; float f; } v; v.u = (unsigned)u << 16; return v.f;
}

// ---- K-layout staging: 32x128 f32 -> bf16 rows, KSTR stride. Lane (sc,sr). ----
__device__ __forceinline__ void k_issue32(const float* __restrict__ g, int sc, int sr,
                                          float4* v) {
#pragma unroll
    for (int it = 0; it < 2; ++it) {
        const float4* gp = reinterpret_cast<const float4*>(
            g + (size_t)(sr + 16 * it) * Dn + sc * 8);
        v[2 * it]     = gp[0];
        v[2 * it + 1] = gp[1];
    }
}
__device__ __forceinline__ void k_write32(unsigned short* lds, int sc, int sr,
                                          const float4* v) {
#pragma unroll
    for (int it = 0; it < 2; ++it) {
        const int r = sr + 16 * it;
        uint4 u;
        u.x = pk2(v[2 * it].x,     v[2 * it].y);
        u.y = pk2(v[2 * it].z,     v[2 * it].w);
        u.z = pk2(v[2 * it + 1].x, v[2 * it + 1].y);
        u.w = pk2(v[2 * it + 1].z, v[2 * it + 1].w);
        *reinterpret_cast<uint4*>(reinterpret_cast<char*>(lds) + r * (KSTR * 2) + sc * 16) = u;
    }
}

// ---- V staging: 32x128 f32 -> vt[d][k] bf16, VSTR stride. Lane (tc,kp). ----
__device__ __forceinline__ void v_issue32(const float* __restrict__ g, int tc, int kp,
                                          float4* v) {
#pragma unroll
    for (int it = 0; it < 2; ++it) {
        const int kr = 2 * kp + 16 * it;
        v[2 * it]     = *reinterpret_cast<const float4*>(g + (size_t)kr * Dn + 4 * tc);
        v[2 * it + 1] = *reinterpret_cast<const float4*>(g + (size_t)(kr + 1) * Dn + 4 * tc);
    }
}
__device__ __forceinline__ void v_write32(unsigned short* vt, int tc, int kp,
                                          const float4* v) {
#pragma unroll
    for (int it = 0; it < 2; ++it) {
        const int kr = 2 * kp + 16 * it;
        const float a4[4] = {v[2 * it].x, v[2 * it].y, v[2 * it].z, v[2 * it].w};
        const float b4[4] = {v[2 * it + 1].x, v[2 * it + 1].y, v[2 * it + 1].z, v[2 * it + 1].w};
#pragma unroll
        for (int j = 0; j < 4; ++j) {
            const int d = 4 * tc + j;
            *reinterpret_cast<unsigned*>(reinterpret_cast<char*>(vt) + d * (VSTR * 2) + kr * 2)
                = pk2(a4[j], b4[j]);
        }
    }
}

__global__ __launch_bounds__(THREADS, 3)
void attn_fused(const float* __restrict__ Q, const float* __restrict__ K,
                const float* __restrict__ V, const int* __restrict__ M,
                float* __restrict__ out) {
    __shared__ __align__(16) unsigned short smem[2 * KT + 2 * VT + WT];
    unsigned short* kb0 = smem;
    unsigned short* kb1 = smem + KT;
    unsigned short* vb0 = smem + 2 * KT;
    unsigned short* vb1 = smem + 2 * KT + VT;
    unsigned short* wl  = smem + 2 * KT + 2 * VT;

    const int tid  = threadIdx.x;
    const int lane = tid & 63;
    const int wv   = tid >> 6;
    const int lr   = lane & 15;
    const int lg   = lane >> 4;

    // XCD-aware remap: each XCD owns 8 heads; qt-major order inside an XCD
    // so co-resident blocks share mask rows (same b) and K/V heads in L2.
    const int wg = blockIdx.x;            // 0..2047
    const int x  = wg & 7;                // XCD (dispatch round-robin assumption)
    const int j  = wg >> 3;               // 0..255
    const int bh = 8 * x + (j & 7);       // 0..63
    const int qt = j >> 3;                // 0..31
    const int b  = bh >> 4;               // H = 16
    const int qbase = qt * BM;

    const float* Qg = Q + ((size_t)bh * Sn + qbase) * Dn;
    const float* Kg = K + (size_t)bh * Sn * Dn;
    const float* Vg = V + (size_t)bh * Sn * Dn;
    const int*   Mg = M + ((size_t)b * Sn + qbase) * Sn;
    float*       Og = out + ((size_t)bh * Sn + qbase) * Dn;
    float*       Wg = out + OUT0 + ((size_t)bh * Sn + qbase) * Sn;

    const float scl2 = 1.4426950408889634f / 11.313708498984761f; // log2(e)/sqrt(D)
    const int qrow = 16 * wv + 4 * lg;    // lane's S rows: qrow+r; cols 16t+lr

    const int sc = tid & 15, sr = tid >> 4;   // K staging lane map
    const int tc = tid & 31, kp = tid >> 5;   // V staging lane map

    const int* mrow[4];
#pragma unroll
    for (int r = 0; r < 4; ++r) mrow[r] = Mg + (size_t)(qrow + r) * Sn + lr;

    // ---------- prologue: Q halves -> vb0/vb1 (K layout), K tile0 -> kb0 ----------
    {
        float4 q0[4], q1[4], kv[4];
        k_issue32(Qg, sc, sr, q0);
        k_issue32(Qg + 32 * Dn, sc, sr, q1);
        k_issue32(Kg, sc, sr, kv);
        k_write32(vb0, sc, sr, q0);
        k_write32(vb1, sc, sr, q1);
        k_write32(kb0, sc, sr, kv);
    }
    __syncthreads();

    s16x4 qf[8];
    {
        const unsigned short* qsrc = (wv >= 2) ? vb1 : vb0;
        const int qr = 16 * (wv & 1) + lr;
#pragma unroll
        for (int dsv = 0; dsv < 8; ++dsv)
            qf[dsv] = *reinterpret_cast<const s16x4*>(
                reinterpret_cast<const char*>(qsrc) + qr * (KSTR * 2) + dsv * 32 + lg * 8);
    }
    __syncthreads();   // Q reads done before vb0/vb1 reused (pass B)

    const f32x4 zero = {0.f, 0.f, 0.f, 0.f};

    // ---------------- pass A: row sums of exp; pack mask bits ----------------
    float rs[4] = {0.f, 0.f, 0.f, 0.f};
    unsigned mb[4][4];
#pragma unroll
    for (int r = 0; r < 4; ++r)
#pragma unroll
        for (int w = 0; w < 4; ++w) mb[r][w] = 0u;

    {
        unsigned short* kcur = kb0;
        unsigned short* knxt = kb1;
#pragma unroll
        for (int w = 0; w < 4; ++w) {
            for (int ti = 0; ti < 16; ++ti) {
                const int to = 16 * w + ti;
                const bool pre = (to < NT - 1);
                float4 kv[4];
                if (pre) k_issue32(Kg + (size_t)(to + 1) * BN * Dn, sc, sr, kv);

                unsigned mvv[2][4];
#pragma unroll
                for (int t = 0; t < 2; ++t)
#pragma unroll
                    for (int r = 0; r < 4; ++r) {
                        const unsigned m = (mrow[r][32 * to + 16 * t] != 0) ? 1u : 0u;
                        mvv[t][r] = m;
                        mb[r][w] |= m << (2 * ti + t);
                    }

                f32x4 s[2] = {zero, zero};
#pragma unroll
                for (int dsv = 0; dsv < 8; ++dsv) {
                    const int koff = dsv * 32 + lg * 8;
#pragma unroll
                    for (int t = 0; t < 2; ++t) {
                        const s16x4 bb = *reinterpret_cast<const s16x4*>(
                            reinterpret_cast<const char*>(kcur) + (16 * t + lr) * (KSTR * 2) + koff);
                        s[t] = __builtin_amdgcn_mfma_f32_16x16x16bf16_1k(qf[dsv], bb, s[t], 0, 0, 0);
                    }
                }
#pragma unroll
                for (int t = 0; t < 2; ++t)
#pragma unroll
                    for (int r = 0; r < 4; ++r)
                        rs[r] += mvv[t][r] ? __builtin_amdgcn_exp2f(s[t][r] * scl2) : 0.f;

                if (pre) k_write32(knxt, sc, sr, kv);
                __syncthreads();
                unsigned short* tmp = kcur; kcur = knxt; knxt = tmp;
            }
        }
    }

    // butterfly over lr bits: full 16-lane sum lands in every lane
    float inv[4];
#pragma unroll
    for (int r = 0; r < 4; ++r) {
        float v = rs[r];
        v += __shfl_xor(v, 1);
        v += __shfl_xor(v, 2);
        v += __shfl_xor(v, 4);
        v += __shfl_xor(v, 8);
        inv[r] = 1.0f / v;
    }

    // ---------------- pass B prologue: K0 -> kb0, V0^T -> vb0 ----------------
    {
        float4 kv[4], vv[4];
        k_issue32(Kg, sc, sr, kv);
        v_issue32(Vg, tc, kp, vv);
        k_write32(kb0, sc, sr, kv);
        v_write32(vb0, tc, kp, vv);
    }
    __syncthreads();

    // ---------------- pass B: weights + PV ----------------
    f32x4 oacc[8];
#pragma unroll
    for (int f = 0; f < 8; ++f) oacc[f] = zero;

    {
        unsigned short* kcur = kb0;
        unsigned short* knxt = kb1;
        unsigned short* vcur = vb0;
        unsigned short* vnxt = vb1;
        const int rowl = lane >> 2;       // W readback: row within wave tile
        const int colg = lane & 3;        // W readback: 4-col group
#pragma unroll
        for (int w = 0; w < 4; ++w) {
            for (int ti = 0; ti < 16; ++ti) {
                const int to = 16 * w + ti;
                const int kc = 32 * to;
                const bool pre = (to < NT - 1);
                float4 kv[4], vv[4];
                if (pre) {
                    k_issue32(Kg + (size_t)(to + 1) * BN * Dn, sc, sr, kv);
                    v_issue32(Vg + (size_t)(to + 1) * BN * Dn, tc, kp, vv);
                }

                f32x4 s[2] = {zero, zero};
#pragma unroll
                for (int dsv = 0; dsv < 8; ++dsv) {
                    const int koff = dsv * 32 + lg * 8;
#pragma unroll
                    for (int t = 0; t < 2; ++t) {
                        const s16x4 bb = *reinterpret_cast<const s16x4*>(
                            reinterpret_cast<const char*>(kcur) + (16 * t + lr) * (KSTR * 2) + koff);
                        s[t] = __builtin_amdgcn_mfma_f32_16x16x16bf16_1k(qf[dsv], bb, s[t], 0, 0, 0);
                    }
                }

#pragma unroll
                for (int t = 0; t < 2; ++t)
#pragma unroll
                    for (int r = 0; r < 4; ++r) {
                        const unsigned mv = (mb[r][w] >> (2 * ti + t)) & 1u;
                        const float e = mv ? __builtin_amdgcn_exp2f(s[t][r] * scl2) : 0.f;
                        reinterpret_cast<unsigned short*>(
                            reinterpret_cast<char*>(wl) + (qrow + r) * (VSTR * 2))[16 * t + lr]
                            = f2bu(e * inv[r]);
                    }
                // no barrier: each wave writes/reads only its own 16 wl rows

#pragma unroll
                for (int kk = 0; kk < 2; ++kk) {
                    const int koff = kk * 32 + lg * 8;
                    const s16x4 aw = *reinterpret_cast<const s16x4*>(
                        reinterpret_cast<const char*>(wl) + (16 * wv + lr) * (VSTR * 2) + koff);
#pragma unroll
                    for (int f = 0; f < 8; ++f) {
                        const s16x4 bv = *reinterpret_cast<const s16x4*>(
                            reinterpret_cast<const char*>(vcur) + (16 * f + lr) * (VSTR * 2) + koff);
                        oacc[f] = __builtin_amdgcn_mfma_f32_16x16x16bf16_1k(aw, bv, oacc[f], 0, 0, 0);
                    }
                }

                // vectorized W store: read bf16 w back from LDS, expand, dwordx4
#pragma unroll
                for (int i = 0; i < 2; ++i) {
                    const ushort4 u = *reinterpret_cast<const ushort4*>(
                        reinterpret_cast<const char*>(wl)
                        + (16 * wv + rowl) * (VSTR * 2) + colg * 8 + 32 * i);
                    float4 o;
                    o.x = b2f(u.x); o.y = b2f(u.y); o.z = b2f(u.z); o.w = b2f(u.w);
                    *reinterpret_cast<float4*>(
                        Wg + (size_t)(16 * wv + rowl) * Sn + kc + colg * 4 + 16 * i) = o;
                }

                if (pre) {
                    k_write32(knxt, sc, sr, kv);
                    v_write32(vnxt, tc, kp, vv);
                }
                __syncthreads();
                unsigned short* tmp = kcur; kcur = knxt; knxt = tmp;
                tmp = vcur; vcur = vnxt; vnxt = tmp;
            }
        }
    }

    // ---------------- epilogue: O ----------------
#pragma unroll
    for (int f = 0; f < 8; ++f)
#pragma unroll
        for (int r = 0; r < 4; ++r)
            Og[(size_t)(qrow + r) * Dn + 16 * f + lr] = oacc[f][r];
}

} // namespace

extern "C" void kernel_launch(void* const* d_in, const int* in_sizes, int n_in,
                              void* d_out, int out_size, void* d_ws, size_t ws_size,
                              hipStream_t stream) {
    (void)in_sizes; (void)n_in; (void)d_ws; (void)ws_size; (void)out_size;
    const float* Q = (const float*)d_in[0];
    const float* K = (const float*)d_in[1];
    const float* V = (const float*)d_in[2];
    const int*   M = (const int*)d_in[3];
    float* out = (float*)d_out;
    attn_fused<<<dim3(2048), dim3(THREADS), 0, stream>>>(Q, K, V, M, out);
}